// Round 1
// baseline (117.549 us; speedup 1.0000x reference)
//
#include <hip/hip_runtime.h>

#define N_ 1024
#define M_ 1024
#define D_ 128
#define NNZ_ 32768
#define H_ 256

typedef _Float16 h2 __attribute__((ext_vector_type(2)));

// ---- K1: fused scatter-mean + both GEMMs -> fp16.
//  blocks 0..63   : hx[16 rows] = X @ W1[:D]
//  blocks 64..191 : 8 segments each — gather edges from E/V into LDS buckets,
//                   build segment sums in LDS, then heb = sums @ W1[D:] / cnt + b1
__global__ __launch_bounds__(256) void gemm_kernel(
        const float* __restrict__ X, const int* __restrict__ V,
        const int* __restrict__ E, const float* __restrict__ W1,
        const float* __restrict__ b1,
        _Float16* __restrict__ hx, _Float16* __restrict__ heb) {
    __shared__ float sA[16][128];      // 8 KB (top uses 16 rows, bottom 8)
    __shared__ int s_bkt[8][128];      // 4 KB bucket (cap 128; counts ~Poisson(32))
    __shared__ int s_cnt[8];
    const int t = threadIdx.x;
    const int b = blockIdx.x;

    if (b < 64) {
        const int row0 = b * 16;
        {
            const float4* A4 = (const float4*)(X + row0 * D_);
            float4* S4 = (float4*)&sA[0][0];
            S4[t] = A4[t];
            S4[t + 256] = A4[t + 256];
        }
        __syncthreads();

        float acc[16];
#pragma unroll
        for (int r = 0; r < 16; ++r) acc[r] = 0.f;

        for (int d = 0; d < D_; d += 4) {
            float w0 = W1[(d + 0) * H_ + t];
            float w1 = W1[(d + 1) * H_ + t];
            float w2 = W1[(d + 2) * H_ + t];
            float w3 = W1[(d + 3) * H_ + t];
#pragma unroll
            for (int r = 0; r < 16; ++r) {
                float4 a = *(const float4*)&sA[r][d];
                acc[r] = fmaf(a.x, w0, acc[r]);
                acc[r] = fmaf(a.y, w1, acc[r]);
                acc[r] = fmaf(a.z, w2, acc[r]);
                acc[r] = fmaf(a.w, w3, acc[r]);
            }
        }
#pragma unroll
        for (int r = 0; r < 16; ++r)
            hx[(row0 + r) * H_ + t] = (_Float16)acc[r];
    } else {
        const int m0 = (b - 64) * 8;

        if (t < 8) s_cnt[t] = 0;
        __syncthreads();

        // gather: scan all edges with coalesced int4 loads, LDS-atomic append
        {
            const int4* E4 = (const int4*)E;
            const int4* V4 = (const int4*)V;
#pragma unroll 4
            for (int it = 0; it < NNZ_ / 4 / 256; ++it) {   // 32 iters
                int idx = it * 256 + t;
                int4 e4 = E4[idx];
                int4 v4 = V4[idx];
                unsigned r;
                r = (unsigned)(e4.x - m0);
                if (r < 8u) { int s = atomicAdd(&s_cnt[r], 1); s_bkt[r][s & 127] = v4.x; }
                r = (unsigned)(e4.y - m0);
                if (r < 8u) { int s = atomicAdd(&s_cnt[r], 1); s_bkt[r][s & 127] = v4.y; }
                r = (unsigned)(e4.z - m0);
                if (r < 8u) { int s = atomicAdd(&s_cnt[r], 1); s_bkt[r][s & 127] = v4.z; }
                r = (unsigned)(e4.w - m0);
                if (r < 8u) { int s = atomicAdd(&s_cnt[r], 1); s_bkt[r][s & 127] = v4.w; }
            }
        }
        __syncthreads();

        // build segment sums; thread owns (r, d): d = t&127, 4 rows per thread
        const int d = t & 127;
        const int half = t >> 7;
#pragma unroll
        for (int p = 0; p < 4; ++p) {
            const int r = p * 2 + half;
            const int cnt = min(s_cnt[r], 128);
            float s = 0.f;
            int i = 0;
            for (; i + 4 <= cnt; i += 4) {
                int v0 = s_bkt[r][i], v1 = s_bkt[r][i + 1];
                int v2 = s_bkt[r][i + 2], v3 = s_bkt[r][i + 3];
                s += X[v0 * D_ + d];
                s += X[v1 * D_ + d];
                s += X[v2 * D_ + d];
                s += X[v3 * D_ + d];
            }
            for (; i < cnt; ++i) s += X[s_bkt[r][i] * D_ + d];
            sA[r][d] = s;
        }
        __syncthreads();

        float acc[8];
#pragma unroll
        for (int r = 0; r < 8; ++r) acc[r] = 0.f;

        const float* __restrict__ W = W1 + D_ * H_;
        for (int dd = 0; dd < D_; dd += 4) {
            float w0 = W[(dd + 0) * H_ + t];
            float w1 = W[(dd + 1) * H_ + t];
            float w2 = W[(dd + 2) * H_ + t];
            float w3 = W[(dd + 3) * H_ + t];
#pragma unroll
            for (int r = 0; r < 8; ++r) {
                float4 a = *(const float4*)&sA[r][dd];
                acc[r] = fmaf(a.x, w0, acc[r]);
                acc[r] = fmaf(a.y, w1, acc[r]);
                acc[r] = fmaf(a.z, w2, acc[r]);
                acc[r] = fmaf(a.w, w3, acc[r]);
            }
        }

        const float bias = b1[t];
#pragma unroll
        for (int r = 0; r < 8; ++r) {
            float inv = 1.0f / fmaxf((float)s_cnt[r], 1.0f);
            heb[(m0 + r) * H_ + t] = (_Float16)(acc[r] * inv + bias);
        }
    }
}

// ---- K2: out[n,m] = sigmoid(b2 + sum_h relu(hx[n,h]+heb[m,h]) * W2[h])
// 64x64 tile / block, 256 threads, 4x4 outputs per thread, full H=256 in LDS fp16.
// Per 4-hp chunk: 9 ds_read_b128 feed 192 VALU instrs (pk_add+pk_max+dot2)
// -> LDS:VALU demand ratio 1.125 per CU (was 1.75 with the old 2x4 tile).
// Grid = 256 blocks = 1 block/CU; 1 wave/SIMD, so deep unroll is free (no
// occupancy cost) and ILP covers ds_read latency.
__global__ __launch_bounds__(256) void big_kernel(
        const _Float16* __restrict__ hx, const _Float16* __restrict__ heb,
        const float* __restrict__ W2, const float* __restrict__ b2,
        float* __restrict__ out) {
    __shared__ _Float16 sA[64][264];   // 264 halves = 528 B row (16B-aligned, shifted)
    __shared__ _Float16 sB[64][264];
    __shared__ h2 sW[H_ / 2];

    const int tid = threadIdx.x;
    const int tx = tid & 15;          // m
    const int ty = tid >> 4;          // n, 0..15
    const int n0 = blockIdx.y * 64;
    const int m0 = blockIdx.x * 64;

    if (tid < H_ / 2) {
        h2 w;
        w.x = (_Float16)W2[2 * tid];
        w.y = (_Float16)W2[2 * tid + 1];
        sW[tid] = w;
    }

    {
        const float4* A4 = (const float4*)hx;   // 32 float4 per 256-half row
        const float4* B4 = (const float4*)heb;
#pragma unroll
        for (int it = 0; it < 8; ++it) {
            int lin = it * 256 + tid;
            int row = lin >> 5;
            int c = lin & 31;
            *(float4*)&sA[row][c * 8] = A4[(n0 + row) * 32 + c];
            *(float4*)&sB[row][c * 8] = B4[(m0 + row) * 32 + c];
        }
    }
    __syncthreads();

    float acc[4][4];
#pragma unroll
    for (int i = 0; i < 4; ++i)
#pragma unroll
        for (int j = 0; j < 4; ++j) acc[i][j] = 0.f;

    union Vn { float4 f4; h2 h[4]; };
    const h2 z = {(_Float16)0.f, (_Float16)0.f};

#pragma unroll 4
    for (int hp = 0; hp < H_ / 2; hp += 4) {
        Vn av[4], bv[4], wv;
        wv.f4 = *(const float4*)&sW[hp];
#pragma unroll
        for (int i = 0; i < 4; ++i) av[i].f4 = *(const float4*)&sA[ty + 16 * i][hp * 2];
#pragma unroll
        for (int j = 0; j < 4; ++j) bv[j].f4 = *(const float4*)&sB[tx + 16 * j][hp * 2];
#pragma unroll
        for (int k = 0; k < 4; ++k) {
#pragma unroll
            for (int i = 0; i < 4; ++i) {
#pragma unroll
                for (int j = 0; j < 4; ++j) {
                    h2 t = av[i].h[k] + bv[j].h[k];
                    t = __builtin_elementwise_max(t, z);
                    acc[i][j] = __builtin_amdgcn_fdot2(t, wv.h[k], acc[i][j], false);
                }
            }
        }
    }

    const float bb = b2[0];
#pragma unroll
    for (int i = 0; i < 4; ++i) {
#pragma unroll
        for (int j = 0; j < 4; ++j) {
            float x = acc[i][j] + bb;
            out[(n0 + ty + 16 * i) * M_ + (m0 + tx + 16 * j)] =
                1.0f / (1.0f + __expf(-x));
        }
    }
}

extern "C" void kernel_launch(void* const* d_in, const int* in_sizes, int n_in,
                              void* d_out, int out_size, void* d_ws, size_t ws_size,
                              hipStream_t stream) {
    const float* X  = (const float*)d_in[0];
    const int*   V  = (const int*)d_in[1];
    const int*   E  = (const int*)d_in[2];
    const float* W1 = (const float*)d_in[3];
    const float* b1 = (const float*)d_in[4];
    const float* W2 = (const float*)d_in[5];
    const float* b2 = (const float*)d_in[6];
    float* out = (float*)d_out;

    char* ws = (char*)d_ws;
    _Float16* hx  = (_Float16*)(ws);             // N*H fp16 = 512 KB
    _Float16* heb = (_Float16*)(ws + 524288);    // M*H fp16 = 512 KB

    gemm_kernel<<<192, 256, 0, stream>>>(X, V, E, W1, b1, hx, heb);

    dim3 bgrid(M_ / 64, N_ / 64);
    big_kernel<<<bgrid, 256, 0, stream>>>(hx, heb, W2, b2, out);
}

// Round 2
// 107.523 us; speedup vs baseline: 1.0932x; 1.0932x over previous
//
#include <hip/hip_runtime.h>

#define N_ 1024
#define M_ 1024
#define D_ 128
#define NNZ_ 32768
#define H_ 256

typedef _Float16 h2 __attribute__((ext_vector_type(2)));

// ---- K1 (unified, balanced): 256 blocks x 256 threads.
// Block b:
//   top:    hx rows [b*4, b*4+4) = X @ W1[:D]
//   bottom: segments [b*4, b*4+4): gather edges (E-scan, V loaded only on hit),
//           segment sums in LDS, heb = sums @ W1[D:] / cnt + b1
// All 256 CUs get exactly one block of uniform work (was 192 blocks, 64 CUs idle).
__global__ __launch_bounds__(256) void gemm_kernel(
        const float* __restrict__ X, const int* __restrict__ V,
        const int* __restrict__ E, const float* __restrict__ W1,
        const float* __restrict__ b1,
        _Float16* __restrict__ hx, _Float16* __restrict__ heb) {
    __shared__ float sA[8][128];       // rows 0-3: X rows; rows 4-7: segment sums
    __shared__ int s_bkt[4][128];      // bucket (cap 128; counts ~Poisson(32))
    __shared__ int s_cnt[4];
    const int t = threadIdx.x;
    const int b = blockIdx.x;
    const int row0 = b * 4;            // top rows
    const int m0 = b * 4;              // segments

    if (t < 4) s_cnt[t] = 0;
    if (t < 128) {                     // stage 4 X rows (128 float4)
        ((float4*)&sA[0][0])[t] = ((const float4*)(X + row0 * D_))[t];
    }
    __syncthreads();

    // ---- edge scan: coalesced int4 E loads; V fetched only when a hit exists
    {
        const int4* E4 = (const int4*)E;
        const int4* V4 = (const int4*)V;
#pragma unroll 4
        for (int it = 0; it < NNZ_ / 4 / 256; ++it) {   // 32 iters
            int idx = it * 256 + t;
            int4 e4 = E4[idx];
            unsigned r0 = (unsigned)(e4.x - m0);
            unsigned r1 = (unsigned)(e4.y - m0);
            unsigned r2 = (unsigned)(e4.z - m0);
            unsigned r3 = (unsigned)(e4.w - m0);
            if ((r0 < 4u) | (r1 < 4u) | (r2 < 4u) | (r3 < 4u)) {
                int4 v4 = V4[idx];
                if (r0 < 4u) { int s = atomicAdd(&s_cnt[r0], 1); s_bkt[r0][s & 127] = v4.x; }
                if (r1 < 4u) { int s = atomicAdd(&s_cnt[r1], 1); s_bkt[r1][s & 127] = v4.y; }
                if (r2 < 4u) { int s = atomicAdd(&s_cnt[r2], 1); s_bkt[r2][s & 127] = v4.z; }
                if (r3 < 4u) { int s = atomicAdd(&s_cnt[r3], 1); s_bkt[r3][s & 127] = v4.w; }
            }
        }
    }
    __syncthreads();

    // ---- segment sums: thread owns (r, d); 2 rows per thread
    {
        const int d = t & 127;
        const int half = t >> 7;
#pragma unroll
        for (int p = 0; p < 2; ++p) {
            const int r = p * 2 + half;
            const int cnt = min(s_cnt[r], 128);
            float s = 0.f;
            int i = 0;
            for (; i + 4 <= cnt; i += 4) {
                int v0 = s_bkt[r][i], v1 = s_bkt[r][i + 1];
                int v2 = s_bkt[r][i + 2], v3 = s_bkt[r][i + 3];
                s += X[v0 * D_ + d];
                s += X[v1 * D_ + d];
                s += X[v2 * D_ + d];
                s += X[v3 * D_ + d];
            }
            for (; i < cnt; ++i) s += X[s_bkt[r][i] * D_ + d];
            sA[4 + r][d] = s;
        }
    }
    __syncthreads();

    // ---- fused 8-row GEMM: rows 0-3 vs W1[:D], rows 4-7 vs W1[D:]
    float acc[8];
#pragma unroll
    for (int r = 0; r < 8; ++r) acc[r] = 0.f;

    const float* __restrict__ Wa = W1;
    const float* __restrict__ Wb = W1 + D_ * H_;
    for (int dd = 0; dd < D_; dd += 4) {
        float wa0 = Wa[(dd + 0) * H_ + t];
        float wa1 = Wa[(dd + 1) * H_ + t];
        float wa2 = Wa[(dd + 2) * H_ + t];
        float wa3 = Wa[(dd + 3) * H_ + t];
        float wb0 = Wb[(dd + 0) * H_ + t];
        float wb1 = Wb[(dd + 1) * H_ + t];
        float wb2 = Wb[(dd + 2) * H_ + t];
        float wb3 = Wb[(dd + 3) * H_ + t];
#pragma unroll
        for (int r = 0; r < 4; ++r) {
            float4 a = *(const float4*)&sA[r][dd];
            acc[r] = fmaf(a.x, wa0, acc[r]);
            acc[r] = fmaf(a.y, wa1, acc[r]);
            acc[r] = fmaf(a.z, wa2, acc[r]);
            acc[r] = fmaf(a.w, wa3, acc[r]);
        }
#pragma unroll
        for (int r = 0; r < 4; ++r) {
            float4 a = *(const float4*)&sA[4 + r][dd];
            acc[4 + r] = fmaf(a.x, wb0, acc[4 + r]);
            acc[4 + r] = fmaf(a.y, wb1, acc[4 + r]);
            acc[4 + r] = fmaf(a.z, wb2, acc[4 + r]);
            acc[4 + r] = fmaf(a.w, wb3, acc[4 + r]);
        }
    }

#pragma unroll
    for (int r = 0; r < 4; ++r)
        hx[(row0 + r) * H_ + t] = (_Float16)acc[r];

    const float bias = b1[t];
#pragma unroll
    for (int r = 0; r < 4; ++r) {
        float inv = 1.0f / fmaxf((float)s_cnt[r], 1.0f);
        heb[(m0 + r) * H_ + t] = (_Float16)(acc[4 + r] * inv + bias);
    }
}

// ---- K2: out[n,m] = sigmoid(b2 + sum_h relu(hx[n,h]+heb[m,h]) * W2[h])
// 64x64 tile / block, 512 threads (2 waves/SIMD for latency hiding), 2x4 per
// thread, full H=256 staged in LDS as fp16. Heavy same-address broadcast in
// the ds_reads makes this VALU-bound (round-1 retile to 4x4/256t regressed:
// 1 wave/SIMD exposed latency; LDS was not the bottleneck).
__global__ __launch_bounds__(512) void big_kernel(
        const _Float16* __restrict__ hx, const _Float16* __restrict__ heb,
        const float* __restrict__ W2, const float* __restrict__ b2,
        float* __restrict__ out) {
    __shared__ _Float16 sA[64][264];   // 264 halves = 528 B row (16B-aligned, shifted)
    __shared__ _Float16 sB[64][264];
    __shared__ h2 sW[H_ / 2];

    const int tid = threadIdx.x;
    const int tx = tid & 15;          // m
    const int ty = tid >> 4;          // n, 0..31
    const int n0 = blockIdx.y * 64;
    const int m0 = blockIdx.x * 64;

    if (tid < H_ / 2) {
        h2 w;
        w.x = (_Float16)W2[2 * tid];
        w.y = (_Float16)W2[2 * tid + 1];
        sW[tid] = w;
    }

    {
        const float4* A4 = (const float4*)hx;   // 32 float4 per 256-half row
        const float4* B4 = (const float4*)heb;
#pragma unroll
        for (int it = 0; it < 4; ++it) {
            int lin = it * 512 + tid;
            int row = lin >> 5;
            int c = lin & 31;
            *(float4*)&sA[row][c * 8] = A4[(n0 + row) * 32 + c];
            *(float4*)&sB[row][c * 8] = B4[(m0 + row) * 32 + c];
        }
    }
    __syncthreads();

    float acc[2][4];
#pragma unroll
    for (int i = 0; i < 2; ++i)
#pragma unroll
        for (int j = 0; j < 4; ++j) acc[i][j] = 0.f;

    union Vn { float4 f4; h2 h[4]; };
    const h2 z = {(_Float16)0.f, (_Float16)0.f};

#pragma unroll 4
    for (int hp = 0; hp < H_ / 2; hp += 4) {
        Vn av[2], bv[4], wv;
        wv.f4 = *(const float4*)&sW[hp];
#pragma unroll
        for (int i = 0; i < 2; ++i) av[i].f4 = *(const float4*)&sA[ty + 32 * i][hp * 2];
#pragma unroll
        for (int j = 0; j < 4; ++j) bv[j].f4 = *(const float4*)&sB[tx + 16 * j][hp * 2];
#pragma unroll
        for (int k = 0; k < 4; ++k) {
#pragma unroll
            for (int i = 0; i < 2; ++i) {
#pragma unroll
                for (int j = 0; j < 4; ++j) {
                    h2 t = av[i].h[k] + bv[j].h[k];
                    t = __builtin_elementwise_max(t, z);
                    acc[i][j] = __builtin_amdgcn_fdot2(t, wv.h[k], acc[i][j], false);
                }
            }
        }
    }

    const float bb = b2[0];
#pragma unroll
    for (int i = 0; i < 2; ++i) {
#pragma unroll
        for (int j = 0; j < 4; ++j) {
            float x = acc[i][j] + bb;
            out[(n0 + ty + 32 * i) * M_ + (m0 + tx + 16 * j)] =
                1.0f / (1.0f + __expf(-x));
        }
    }
}

extern "C" void kernel_launch(void* const* d_in, const int* in_sizes, int n_in,
                              void* d_out, int out_size, void* d_ws, size_t ws_size,
                              hipStream_t stream) {
    const float* X  = (const float*)d_in[0];
    const int*   V  = (const int*)d_in[1];
    const int*   E  = (const int*)d_in[2];
    const float* W1 = (const float*)d_in[3];
    const float* b1 = (const float*)d_in[4];
    const float* W2 = (const float*)d_in[5];
    const float* b2 = (const float*)d_in[6];
    float* out = (float*)d_out;

    char* ws = (char*)d_ws;
    _Float16* hx  = (_Float16*)(ws);             // N*H fp16 = 512 KB
    _Float16* heb = (_Float16*)(ws + 524288);    // M*H fp16 = 512 KB

    gemm_kernel<<<256, 256, 0, stream>>>(X, V, E, W1, b1, hx, heb);

    dim3 bgrid(M_ / 64, N_ / 64);
    big_kernel<<<bgrid, 512, 0, stream>>>(hx, heb, W2, b2, out);
}